// Round 11
// baseline (931.826 us; speedup 1.0000x reference)
//
#include <hip/hip_runtime.h>
#include <hip/hip_bf16.h>

typedef unsigned int uint;
typedef unsigned short ushort;

constexpr int Bn = 256, Sn = 512, Vn = 32000, Dn = 100, Hn = 75, Ln = 128;
constexpr int KP = 96;    // weight row K-pad (3 x 32) for MFMA B-operands
constexpr int W2S = 80;   // w2p row stride (f16)
constexpr int HS  = 104;  // h_lds row stride (f16): 52-word rows -> ~2-way b128

// workspace layout (float units) -- only small weight buffers now
constexpr size_t OFF_W2P = 0;              // 80*80 f16 = 3200 f
constexpr size_t OFF_WOH = 3200;           // 80*96 f16 = 3840 f
constexpr size_t OFF_WFH = OFF_WOH + 3840; // 128*96 f16 = 6144 f

typedef __attribute__((ext_vector_type(2))) _Float16 half2_t;
typedef __attribute__((ext_vector_type(8))) _Float16 half8;
typedef __attribute__((ext_vector_type(4))) float floatx4;

__device__ __forceinline__ ushort f2h(float f){
    union { _Float16 h; ushort u; } v; v.h = (_Float16)f; return v.u;
}
__device__ __forceinline__ half8 as_h8(uint4 u){
    union { uint4 u; half8 h; } v; v.u = u; return v.h;
}
__device__ __forceinline__ float sigmoidf(float z){
    return __builtin_amdgcn_rcpf(1.f + __expf(-z));
}

// ---------------------------------------------------------------------------
// Prep: W2 -> [80][80] f16 (pad 0), Wo -> [80][96] f16, Wfc -> [128][96] f16.
// (h_all and embW are gone -- h history lives in LDS, xp computed in-kernel.)
// ---------------------------------------------------------------------------
__global__ __launch_bounds__(256) void k_wprep(
    const float* __restrict__ W2, const float* __restrict__ Wo,
    const float* __restrict__ Wfc, ushort* __restrict__ w2p,
    ushort* __restrict__ woh, ushort* __restrict__ wfh)
{
    const int tid = blockIdx.x*256 + threadIdx.x;
    const int stride = gridDim.x*256;
    for (int i = tid; i < 80*W2S; i += stride){
        int r = i / W2S, k = i % W2S;
        w2p[i] = (r < Hn && k < Hn) ? f2h(W2[r*Hn + k]) : (ushort)0;
    }
    for (int i = tid; i < 80*KP; i += stride){
        int r = i / KP, k = i % KP;
        woh[i] = (r < Hn && k < Hn) ? f2h(Wo[r*Hn + k]) : (ushort)0;
    }
    for (int i = tid; i < Ln*KP; i += stride){
        int l = i / KP, k = i % KP;
        wfh[i] = (k < Hn) ? f2h(Wfc[l*Hn + k]) : (ushort)0;
    }
}

// ---------------------------------------------------------------------------
// FULLY FUSED: xp projection + scan + epilogue. 256 threads, 1 block/batch row.
// r10 diagnostic: total - fused = 132us of wprep+embproj+gaps; embproj is the
// suspect. Fix: DELETE embproj/embW -- waves 1-3 compute xp[c+1] (fp32, same
// 4-chain summation order as embproj -> identical numerics) from emb/W1
// (L2/L3-hot broadcast reads) into the LDS double buffer WHILE wave 0 scans
// chunk c (~15k cy of work vs 49k cy scan budget -> fully hidden).
// Second fusion win: h history stays in LDS ([512][104] f16, 104KB; total
// LDS 146KB <= 160KB) -- removes 2 global stores/step from the scan chain
// and 50MB of HBM round-trip; epilogue reads h from LDS. o_lds aliases the
// then-dead xpb region. Scan itself is r6-EXACT (best measured structure).
// ---------------------------------------------------------------------------
__global__ __attribute__((amdgpu_flat_work_group_size(256,256)))
__attribute__((amdgpu_waves_per_eu(1,1)))
void k_rnn(
    const int* __restrict__ X, const float* __restrict__ emb,
    const float* __restrict__ W1, const float* __restrict__ b1,
    const float* __restrict__ b2, const ushort* __restrict__ w2p,
    const ushort* __restrict__ woh, const ushort* __restrict__ wfh,
    const float* __restrict__ bo, const float* __restrict__ bfc,
    float* __restrict__ out)
{
    const int b   = blockIdx.x;
    const int tid = threadIdx.x;
    const int L   = tid & 63;
    const int wv  = tid >> 6;
    const int m   = L & 15;
    const int g   = L >> 4;
    __shared__ int sX[Sn];                          // 2 KB
    __shared__ __align__(16) float xpb[2][64*80];   // 40 KB xp double buffer
    __shared__ __align__(16) ushort hls[Sn*HS];     // 104 KB h history (f16)

    for (int i = tid; i < Sn; i += 256) sX[i] = X[b*Sn + i];
    // zero h pad cols 80..95 (read by epilogue k-step 2)
    for (int i = tid; i < Sn*8; i += 256){
        int row = i >> 3, cw = i & 7;
        ((uint*)hls)[row*(HS/2) + 40 + cw] = 0u;
    }

    // per-lane xp bias + W1 row pointers (row L and clamped row 64+L)
    const float bl1 = b1[L] + b2[L];
    const float bl2 = (L < 11) ? (b1[64 + L] + b2[64 + L]) : 0.f;
    const float4* wrow_a = (const float4*)(W1 + (size_t)L*Dn);
    const int j2 = (64 + L < Hn) ? (64 + L) : (Hn - 1);
    const float4* wrow_b = (const float4*)(W1 + (size_t)j2*Dn);

    // xp[tt][j] for chunk c, tokens [lo,hi): fp32, embproj-identical math
    auto compute_xp = [&](int c, int lo, int hi){
        float* buf = xpb[c & 1];
        const int base = c*64;
        for (int tt = lo; tt < hi; ++tt){
            int tok = sX[base + tt];
            const float4* er = (const float4*)(emb + (size_t)tok*Dn);
            float a0 = bl1, a1 = 0.f, a2 = 0.f, a3 = 0.f;
            float c0 = bl2, c1 = 0.f, c2 = 0.f, c3 = 0.f;
            #pragma unroll
            for (int d = 0; d < Dn/4; ++d){
                float4 e4 = er[d], w4 = wrow_a[d], v4 = wrow_b[d];
                a0 += w4.x*e4.x; a1 += w4.y*e4.y;
                a2 += w4.z*e4.z; a3 += w4.w*e4.w;
                c0 += v4.x*e4.x; c1 += v4.y*e4.y;
                c2 += v4.z*e4.z; c3 += v4.w*e4.w;
            }
            buf[tt*80 + L] = (a0+a1) + (a2+a3);
            if (L < 16) buf[tt*80 + 64 + L] = (L < 11) ? ((c0+c1)+(c2+c3)) : 0.f;
        }
    };

    // B-fragments (wave 0 only): lane holds W2[n=16t+m][k0..k0+7], k0=ks*32+g*8
    half8 bfr[5][3];
    if (wv == 0){
        #pragma unroll
        for (int t = 0; t < 5; ++t){
            #pragma unroll
            for (int ks = 0; ks < 3; ++ks){
                int k0 = ks*32 + g*8;
                half8 bv = {};
                if (k0 < 80) bv = *(const half8*)(w2p + (size_t)(16*t + m)*W2S + k0);
                bfr[t][ks] = bv;                 // k0>=80: A is zero there anyway
            }
        }
    }
    __syncthreads();                             // sX visible

    // prologue: chunk 0 split across all 4 waves (16 tokens each)
    compute_xp(0, wv*16, wv*16 + 16);

    // bpermute byte-addresses (loop-invariant):
    // af0/af2 pair j <- src lane 2*(4g+j)  -> addr 32g+8j; af1: +128B
    int va0 = 32*g,      va1 = 32*g + 8,  va2 = 32*g + 16, va3 = 32*g + 24;
    int vb0 = va0 + 128, vb1 = va1 + 128, vb2 = va2 + 128, vb3 = va3 + 128;

    const floatx4 zero4 = {};
    uint4 A0 = {}, A1 = {}, A2 = {};             // h_{-1} = 0

    for (int c = 0; c < 8; ++c){
        __syncthreads();                 // xp[c] ready (computed during c-1)
        if (wv != 0){
            // waves 1-3: compute next chunk's xp (hidden behind wave 0's scan)
            if (c < 7){
                int lo = (wv == 1) ? 0  : (wv == 2) ? 22 : 43;
                int hi = (wv == 1) ? 22 : (wv == 2) ? 43 : 64;
                compute_xp(c + 1, lo, hi);
            }
        } else {
            const float* xp = xpb[c & 1];
            // xp prefetch pipeline (2 deep), affine LDS addresses
            float x1c = xp[L];
            float x2c = (L < 16) ? xp[64 + L] : 0.f;
            float x1n = xp[80 + L];
            float x2n = (L < 16) ? xp[80 + 64 + L] : 0.f;
            for (int t = 0; t < 64; ++t){
                int pf = (t + 2 < 64) ? t + 2 : 63;  // clamped, never consumed
                float x1f = xp[pf*80 + L];
                float x2f = (L < 16) ? xp[pf*80 + 64 + L] : 0.f;

                half8 af0 = as_h8(A0), af1 = as_h8(A1), af2 = as_h8(A2);

                // y = W2 @ h : 5 output tiles x 3 K-steps (r6-exact chaining)
                floatx4 acc0, acc1, acc2, acc3, acc4;
                acc0 = __builtin_amdgcn_mfma_f32_16x16x32_f16(af0, bfr[0][0], zero4, 0,0,0);
                acc1 = __builtin_amdgcn_mfma_f32_16x16x32_f16(af0, bfr[1][0], zero4, 0,0,0);
                acc2 = __builtin_amdgcn_mfma_f32_16x16x32_f16(af0, bfr[2][0], zero4, 0,0,0);
                acc3 = __builtin_amdgcn_mfma_f32_16x16x32_f16(af0, bfr[3][0], zero4, 0,0,0);
                acc4 = __builtin_amdgcn_mfma_f32_16x16x32_f16(af0, bfr[4][0], zero4, 0,0,0);
                acc0 = __builtin_amdgcn_mfma_f32_16x16x32_f16(af1, bfr[0][1], acc0, 0,0,0);
                acc1 = __builtin_amdgcn_mfma_f32_16x16x32_f16(af1, bfr[1][1], acc1, 0,0,0);
                acc2 = __builtin_amdgcn_mfma_f32_16x16x32_f16(af1, bfr[2][1], acc2, 0,0,0);
                acc3 = __builtin_amdgcn_mfma_f32_16x16x32_f16(af1, bfr[3][1], acc3, 0,0,0);
                acc4 = __builtin_amdgcn_mfma_f32_16x16x32_f16(af1, bfr[4][1], acc4, 0,0,0);
                acc0 = __builtin_amdgcn_mfma_f32_16x16x32_f16(af2, bfr[0][2], acc0, 0,0,0);
                acc1 = __builtin_amdgcn_mfma_f32_16x16x32_f16(af2, bfr[1][2], acc1, 0,0,0);
                acc2 = __builtin_amdgcn_mfma_f32_16x16x32_f16(af2, bfr[2][2], acc2, 0,0,0);
                acc3 = __builtin_amdgcn_mfma_f32_16x16x32_f16(af2, bfr[3][2], acc3, 0,0,0);
                acc4 = __builtin_amdgcn_mfma_f32_16x16x32_f16(af2, bfr[4][2], acc4, 0,0,0);

                // lane-local extraction: y[L] = acc_g[0]; y[64+m] = acc4[0]
                float y1 = (L < 32) ? ((L < 16) ? acc0[0] : acc1[0])
                                    : ((L < 48) ? acc2[0] : acc3[0]);
                float y2 = acc4[0];

                float h1 = sigmoidf(y1 + x1c);
                float h2 = sigmoidf(y2 + x2c);
                if (L >= 11) h2 = 0.f;               // cols 75..79 pad -> 0
                ushort u1 = f2h(h1);
                ushort u2 = f2h(h2);
                int s = c*64 + t;
                hls[(size_t)s*HS + L] = u1;          // h history -> LDS
                if (L < 16) hls[(size_t)s*HS + 64 + L] = u2;

                // pair adjacent lanes' f16 via DPP quad_perm [1,0,3,2]
                uint v1 = u1, v2 = u2;
                uint pr1 = (uint)__builtin_amdgcn_update_dpp(0, (int)v1, 0xB1, 0xF, 0xF, true);
                uint pr2 = (uint)__builtin_amdgcn_update_dpp(0, (int)v2, 0xB1, 0xF, 0xF, true);
                int q1 = (int)(v1 | (pr1 << 16));
                int q2 = (int)(v2 | (pr2 << 16));

                // rebuild A-fragments for step s+1: 12 independent bpermutes
                A0.x = (uint)__builtin_amdgcn_ds_bpermute(va0, q1);
                A0.y = (uint)__builtin_amdgcn_ds_bpermute(va1, q1);
                A0.z = (uint)__builtin_amdgcn_ds_bpermute(va2, q1);
                A0.w = (uint)__builtin_amdgcn_ds_bpermute(va3, q1);
                A1.x = (uint)__builtin_amdgcn_ds_bpermute(vb0, q1);
                A1.y = (uint)__builtin_amdgcn_ds_bpermute(vb1, q1);
                A1.z = (uint)__builtin_amdgcn_ds_bpermute(vb2, q1);
                A1.w = (uint)__builtin_amdgcn_ds_bpermute(vb3, q1);
                A2.x = (uint)__builtin_amdgcn_ds_bpermute(va0, q2);
                A2.y = (uint)__builtin_amdgcn_ds_bpermute(va1, q2);
                A2.z = (uint)__builtin_amdgcn_ds_bpermute(va2, q2);
                A2.w = (uint)__builtin_amdgcn_ds_bpermute(va3, q2);

                x1c = x1n; x2c = x2n; x1n = x1f; x2n = x2f;
            }
        }
    }
    __syncthreads();                     // h history complete & visible

    // ---- fused epilogue: 8 x 64-row chunks; h from LDS; O in dead xpb ----
    ushort* ot = (ushort*)xpb + wv*(16*HS);
    for (int i = L; i < 128; i += 64){   // zero O pad cols 80..95 once
        int row = i >> 3, cw = i & 7;
        *(uint*)&ot[row*HS + 80 + cw*2] = 0u;
    }
    for (int it = 0; it < 8; ++it){
        const int r0l = it*64 + wv*16;   // local H-row base
        // Phase 1: Z = H @ Wo^T  (A from LDS h history)
        floatx4 acc1[5] = {};
        #pragma unroll
        for (int ks = 0; ks < 3; ++ks){
            half8 a = *(const half8*)(hls + (size_t)(r0l + m)*HS + ks*32 + g*8);
            #pragma unroll
            for (int t = 0; t < 5; ++t){
                half8 bt = *(const half8*)(woh + (16*t + m)*KP + ks*32 + g*8);
                acc1[t] = __builtin_amdgcn_mfma_f32_16x16x32_f16(a, bt, acc1[t], 0, 0, 0);
            }
        }
        // bo + sigmoid -> O (f16, C layout)
        #pragma unroll
        for (int t = 0; t < 5; ++t){
            int n = 16*t + m;
            float bias = (n < Hn) ? bo[n] : 0.f;
            #pragma unroll
            for (int r = 0; r < 4; ++r){
                int row = g*4 + r;
                float o = sigmoidf(acc1[t][r] + bias);
                if (n >= Hn) o = 0.f;            // pad rows -> z=0 -> 0.5; kill
                ot[row*HS + n] = f2h(o);
            }
        }
        // wave-local LDS RAW: in-order DS pipe within a wave; no barrier
        // Phase 2: OUT = O @ Wfc^T
        floatx4 acc2[8] = {};
        #pragma unroll
        for (int ks = 0; ks < 3; ++ks){
            half8 a = *(const half8*)(ot + m*HS + ks*32 + g*8);
            #pragma unroll
            for (int t = 0; t < 8; ++t){
                half8 bt = *(const half8*)(wfh + (16*t + m)*KP + ks*32 + g*8);
                acc2[t] = __builtin_amdgcn_mfma_f32_16x16x32_f16(a, bt, acc2[t], 0, 0, 0);
            }
        }
        // bfc + store
        float* orow = out + ((size_t)b*Sn + r0l)*Ln;
        #pragma unroll
        for (int t = 0; t < 8; ++t){
            float bias = bfc[16*t + m];
            #pragma unroll
            for (int r = 0; r < 4; ++r){
                int row = g*4 + r;
                orow[(size_t)row*Ln + 16*t + m] = acc2[t][r] + bias;
            }
        }
    }
}

extern "C" void kernel_launch(void* const* d_in, const int* in_sizes, int n_in,
                              void* d_out, int out_size, void* d_ws, size_t ws_size,
                              hipStream_t stream)
{
    const int*   X   = (const int*)d_in[0];
    const float* emb = (const float*)d_in[1];
    const float* W1  = (const float*)d_in[2];
    const float* b1  = (const float*)d_in[3];
    const float* W2  = (const float*)d_in[4];
    const float* b2  = (const float*)d_in[5];
    const float* Wo  = (const float*)d_in[6];
    const float* bo  = (const float*)d_in[7];
    const float* Wfc = (const float*)d_in[8];
    const float* bfc = (const float*)d_in[9];
    float* out = (float*)d_out;
    float* ws  = (float*)d_ws;

    ushort* w2p = (ushort*)(ws + OFF_W2P);
    ushort* woh = (ushort*)(ws + OFF_WOH);
    ushort* wfh = (ushort*)(ws + OFF_WFH);

    k_wprep<<<dim3(32), dim3(256), 0, stream>>>(W2, Wo, Wfc, w2p, woh, wfh);
    k_rnn<<<dim3(Bn), dim3(256), 0, stream>>>(X, emb, W1, b1, b2, w2p,
                                              woh, wfh, bo, bfc, out);
}